// Round 17
// baseline (31.935 us; speedup 1.0000x reference)
//
#include <hip/hip_runtime.h>

// DIAGNOSTIC ROUND (R12-best structure): the LDS staging loop runs
// STAGE_REPS=16 per half (idempotent re-pack of identical bytes; barriers
// prevent store-merging). dur = 15.3 + 30*X_half. Compute section unchanged.

typedef _Float16 f16x4 __attribute__((ext_vector_type(4)));
typedef _Float16 f16x8 __attribute__((ext_vector_type(8)));
typedef float    f32x16 __attribute__((ext_vector_type(16)));

#define BATCH 8
#define NPTS 4096
#define THREADS 512
#define WAVES 8
#define HALF_PTS 2048
#define HALF_TILES (HALF_PTS/32)     // 64
#define K1_BLOCKS 256
#define STAGE_REPS 16                // DIAGNOSTIC multiplier

__device__ __forceinline__ float min3f(float a, float b, float c) {
    return fminf(fminf(a, b), c);
}

__global__ __launch_bounds__(THREADS, 8) void cd_mfma(
        const float* __restrict__ pred,
        const float* __restrict__ targ,
        float* __restrict__ Bsum) {
    __shared__ uint4 sdb[HALF_PTS];
    __shared__ float wred[WAVES];
    const int bx   = blockIdx.x;
    const int tid  = threadIdx.x;
    const int dirb = bx >> 4;
    const int ctg  = bx & 15;
    const int wave = tid >> 6;
    const int lane = tid & 63;
    const int dir  = dirb >> 3;
    const int b    = dirb & 7;
    const float* Qraw = (dir ? targ : pred) + (size_t)b * NPTS * 3;
    const float* Draw = (dir ? pred : targ) + (size_t)b * NPTS * 3;

    const int q = (ctg * WAVES + wave) * 32 + (lane & 31);
    const float* qp = Qraw + (size_t)q * 3;
    _Float16 qhx = (_Float16)qp[0], qhy = (_Float16)qp[1], qhz = (_Float16)qp[2];
    float xr = (float)qhx, yr = (float)qhy, zr = (float)qhz;
    float nq = fmaf(xr, xr, fmaf(yr, yr, zr * zr));
    _Float16 mx = (_Float16)(-2.f * xr), my = (_Float16)(-2.f * yr),
             mz = (_Float16)(-2.f * zr), one = (_Float16)1.f, zz = (_Float16)0.f;
    f16x4 Bf = (lane < 32) ? (f16x4){mx, my, mz, one}
                           : (f16x4){one, zz, zz, zz};

    const f32x16 Z = {};
    const float inf = __uint_as_float(0x7F800000u);
    float m = inf;
    auto fold = [&](const f32x16& a) {
        float s0 = min3f(a[0],  a[1],  a[2]);
        float s1 = min3f(a[3],  a[4],  a[5]);
        float s2 = min3f(a[6],  a[7],  a[8]);
        float s3 = min3f(a[9],  a[10], a[11]);
        float s4 = min3f(a[12], a[13], a[14]);
        float t0 = min3f(s0, s1, s2);
        float t1 = min3f(s3, s4, a[15]);
        m = min3f(m, t0, t1);
    };

    const char* sb = (const char*)sdb;
    const int off0 = (lane & 31) * 16 + ((lane >> 5) << 3);

    #pragma unroll 1
    for (int h = 0; h < 2; ++h) {
        if (h) __syncthreads();

        #pragma unroll 1
        for (int rep = 0; rep < STAGE_REPS; ++rep) {   // DIAGNOSTIC
            for (int i = tid; i < HALF_PTS; i += THREADS) {
                const float* p = Draw + (size_t)(h * HALF_PTS + i) * 3;
                _Float16 hx = (_Float16)p[0], hy = (_Float16)p[1], hz = (_Float16)p[2];
                float xf = (float)hx, yf = (float)hy, zf = (float)hz;
                float w  = fmaf(xf, xf, fmaf(yf, yf, zf * zf));
                _Float16 hhi = (_Float16)w;
                _Float16 hlo = (_Float16)(w - (float)hhi);
                f16x8 pkt = {hx, hy, hz, hhi, hlo,
                             (_Float16)0.f, (_Float16)0.f, (_Float16)0.f};
                sdb[i] = __builtin_bit_cast(uint4, pkt);
            }
            __syncthreads();
        }

        int off = off0;
        auto rd = [&]() {
            f16x4 v = *(const f16x4*)(sb + off); off += 512; return v;
        };
        f32x16 acc0 = __builtin_amdgcn_mfma_f32_32x32x8f16(rd(), Bf, Z, 0, 0, 0);
        f32x16 acc1 = __builtin_amdgcn_mfma_f32_32x32x8f16(rd(), Bf, Z, 0, 0, 0);
        #pragma unroll 4
        for (int j = 2; j < HALF_TILES; j += 2) {
            fold(acc0);
            acc0 = __builtin_amdgcn_mfma_f32_32x32x8f16(rd(), Bf, Z, 0, 0, 0);
            fold(acc1);
            acc1 = __builtin_amdgcn_mfma_f32_32x32x8f16(rd(), Bf, Z, 0, 0, 0);
        }
        fold(acc0);
        fold(acc1);
        __syncthreads();
    }

    m = fminf(m, __shfl_xor(m, 32, 64));
    float d = sqrtf(fmaxf(m + nq, 0.f));
    d += __shfl_xor(d, 16, 64);
    d += __shfl_xor(d,  8, 64);
    d += __shfl_xor(d,  4, 64);
    d += __shfl_xor(d,  2, 64);
    d += __shfl_xor(d,  1, 64);
    if (lane == 0) wred[wave] = d;
    __syncthreads();
    if (tid == 0) {
        float s = ((wred[0] + wred[1]) + (wred[2] + wred[3]))
                + ((wred[4] + wred[5]) + (wred[6] + wred[7]));
        Bsum[bx] = s;
    }
}

__global__ __launch_bounds__(256) void cd_final(
        const float* __restrict__ Bsum, float* __restrict__ out) {
    const int tid = threadIdx.x;
    float s = Bsum[tid];
    __shared__ float red[256];
    red[tid] = s;
    __syncthreads();
    for (int off = 128; off > 0; off >>= 1) {
        if (tid < off) red[tid] += red[tid + off];
        __syncthreads();
    }
    if (tid == 0) out[0] = red[0] * (1.0f / (float)(BATCH * NPTS));
}

extern "C" void kernel_launch(void* const* d_in, const int* in_sizes, int n_in,
                              void* d_out, int out_size, void* d_ws, size_t ws_size,
                              hipStream_t stream) {
    const float* pred = (const float*)d_in[0];
    const float* targ = (const float*)d_in[1];
    float* Bsum = (float*)d_ws;
    float* out  = (float*)d_out;

    cd_mfma<<<K1_BLOCKS, THREADS, 0, stream>>>(pred, targ, Bsum);
    cd_final<<<1, 256, 0, stream>>>(Bsum, out);
}

// Round 18
// 16.173 us; speedup vs baseline: 1.9746x; 1.9746x over previous
//
#include <hip/hip_runtime.h>

// Chamfer distance, B=8, N=M=4096, fp32 in/out — MFMA f16 K=8, conflict-free,
// 2 dispatches, in-block db-half merge (no P buffer).
//   d^2 = |q~|^2 + (hi+lo) - 2 q~.b~   via  v_mfma_f32_32x32x8_f16
//   A (32x8): lanes 0-31 row=lane k0-3 {x,y,z,hi}; lanes 32-63 k4-7 {lo,0,0,0}
//   B (8x32): col=lane&31 {-2x,-2y,-2z,1 | 1,0,0,0}
//   C: col = lane&31 (query); in-lane min over rows + shfl32 merge.
// LDS: tile-split layout, tile t = 64 u64 [lo rows 0-31 | hi rows 0-31];
//   read (t*64+lane)*8 -> consecutive 8B/lane = conflict-free.
// K1 cd_mfma: 256 blocks (dirb, qgroup of 256 q) x 512 thr. Stage full 64KB
//   db; waves 0-3 db-half 0, waves 4-7 half 1; wave = 2 coltiles (2 B-frags
//   per A-read); halves merged via 2KB LDS; sqrt+sum -> Bsum[256]. No atomics.
// K2 cd_final: 256 thr tree-sum -> loss.

typedef _Float16 f16x4 __attribute__((ext_vector_type(4)));
typedef float    f32x16 __attribute__((ext_vector_type(16)));

#define BATCH 8
#define NPTS 4096
#define THREADS 512
#define HALF_TILES 64
#define K1_BLOCKS 256                // 16 dirb x 16 qgroups

__device__ __forceinline__ float min3f(float a, float b, float c) {
    return fminf(fminf(a, b), c);    // -> v_min3_f32
}

__global__ __launch_bounds__(THREADS, 4) void cd_mfma(
        const float* __restrict__ pred,
        const float* __restrict__ targ,
        float* __restrict__ Bsum) {
    __shared__ unsigned long long sdb[NPTS * 2];   // 64 KB tile-split db
    __shared__ float wpA[4][64], wpB[4][64];       // half-merge buffers
    __shared__ float wred[4];
    const int bx   = blockIdx.x;       // 0..255
    const int tid  = threadIdx.x;
    const int dirb = bx >> 4;          // 0..15
    const int qg   = bx & 15;          // 0..15
    const int wave = tid >> 6;         // 0..7
    const int lane = tid & 63;
    const int wsel = wave & 3;
    const int hsel = wave >> 2;        // db half this wave scans
    const int dir  = dirb >> 3;
    const int b    = dirb & 7;
    const float* Qraw = (dir ? targ : pred) + (size_t)b * NPTS * 3;
    const float* Draw = (dir ? pred : targ) + (size_t)b * NPTS * 3;

    // ---- stage + f16-pack full db into tile-split layout ----
    for (int i = tid; i < NPTS; i += THREADS) {
        const float* p = Draw + (size_t)i * 3;
        _Float16 hx = (_Float16)p[0], hy = (_Float16)p[1], hz = (_Float16)p[2];
        float xf = (float)hx, yf = (float)hy, zf = (float)hz;
        float w  = fmaf(xf, xf, fmaf(yf, yf, zf * zf));
        _Float16 hhi = (_Float16)w;
        _Float16 hlo = (_Float16)(w - (float)hhi);
        f16x4 lo4 = {hx, hy, hz, hhi};
        f16x4 hi4 = {hlo, (_Float16)0.f, (_Float16)0.f, (_Float16)0.f};
        const int t = i >> 5, r = i & 31;
        sdb[t * 64 + r]      = __builtin_bit_cast(unsigned long long, lo4);
        sdb[t * 64 + 32 + r] = __builtin_bit_cast(unsigned long long, hi4);
    }

    // ---- query packets: wave owns coltiles 2*wsel, 2*wsel+1 of this qgroup ----
    const int q0 = qg * 256 + wsel * 64 + (lane & 31);
    const int q1 = q0 + 32;
    float nq0, nq1;
    auto mkB = [&](int q, float& nq) -> f16x4 {
        const float* qp = Qraw + (size_t)q * 3;
        _Float16 qx = (_Float16)qp[0], qy = (_Float16)qp[1], qz = (_Float16)qp[2];
        float xr = (float)qx, yr = (float)qy, zr = (float)qz;
        nq = fmaf(xr, xr, fmaf(yr, yr, zr * zr));
        _Float16 mx = (_Float16)(-2.f * xr), my = (_Float16)(-2.f * yr),
                 mz = (_Float16)(-2.f * zr), one = (_Float16)1.f,
                 zz = (_Float16)0.f;
        return (lane < 32) ? (f16x4){mx, my, mz, one}
                           : (f16x4){one, zz, zz, zz};
    };
    f16x4 B0 = mkB(q0, nq0);
    f16x4 B1 = mkB(q1, nq1);

    __syncthreads();

    const f32x16 Z = {};
    const float inf = __uint_as_float(0x7F800000u);
    float m0 = inf, m1 = inf;
    auto fold = [&](const f32x16& a, float& m) {
        float s0 = min3f(a[0],  a[1],  a[2]);
        float s1 = min3f(a[3],  a[4],  a[5]);
        float s2 = min3f(a[6],  a[7],  a[8]);
        float s3 = min3f(a[9],  a[10], a[11]);
        float s4 = min3f(a[12], a[13], a[14]);
        float t0 = min3f(s0, s1, s2);
        float t1 = min3f(s3, s4, a[15]);
        m = min3f(m, t0, t1);
    };

    int idx = hsel * (HALF_TILES * 64) + lane;
    auto rdA = [&]() {
        f16x4 v = __builtin_bit_cast(f16x4, sdb[idx]);
        idx += 64;
        return v;
    };

    // 64 tiles (this wave's half), 2-deep x 2-B MFMA pipeline
    f16x4 A0 = rdA();
    f32x16 a00 = __builtin_amdgcn_mfma_f32_32x32x8f16(A0, B0, Z, 0, 0, 0);
    f32x16 a01 = __builtin_amdgcn_mfma_f32_32x32x8f16(A0, B1, Z, 0, 0, 0);
    f16x4 A1 = rdA();
    f32x16 a10 = __builtin_amdgcn_mfma_f32_32x32x8f16(A1, B0, Z, 0, 0, 0);
    f32x16 a11 = __builtin_amdgcn_mfma_f32_32x32x8f16(A1, B1, Z, 0, 0, 0);
    #pragma unroll 4
    for (int j = 2; j < HALF_TILES; j += 2) {
        f16x4 An = rdA();
        fold(a00, m0); fold(a01, m1);
        a00 = __builtin_amdgcn_mfma_f32_32x32x8f16(An, B0, Z, 0, 0, 0);
        a01 = __builtin_amdgcn_mfma_f32_32x32x8f16(An, B1, Z, 0, 0, 0);
        f16x4 Am = rdA();
        fold(a10, m0); fold(a11, m1);
        a10 = __builtin_amdgcn_mfma_f32_32x32x8f16(Am, B0, Z, 0, 0, 0);
        a11 = __builtin_amdgcn_mfma_f32_32x32x8f16(Am, B1, Z, 0, 0, 0);
    }
    fold(a00, m0); fold(a01, m1);
    fold(a10, m0); fold(a11, m1);

    // merge lane-halves; publish this wave's half-min; merge halves in-block
    m0 = fminf(m0, __shfl_xor(m0, 32, 64));
    m1 = fminf(m1, __shfl_xor(m1, 32, 64));
    if (lane < 32) {
        float (*wp)[64] = hsel ? wpB : wpA;
        wp[wsel][lane]      = m0;
        wp[wsel][32 + lane] = m1;
    }
    __syncthreads();
    if (wave < 4) {
        const int l = lane & 31;
        float d = 0.f;
        if (lane < 32) {
            float mm0 = fminf(wpA[wave][l],      wpB[wave][l]);
            float mm1 = fminf(wpA[wave][32 + l], wpB[wave][32 + l]);
            d = sqrtf(fmaxf(mm0 + nq0, 0.f)) + sqrtf(fmaxf(mm1 + nq1, 0.f));
        }
        d += __shfl_xor(d, 32, 64);   // lanes>=32 contribute 0
        d += __shfl_xor(d, 16, 64);
        d += __shfl_xor(d,  8, 64);
        d += __shfl_xor(d,  4, 64);
        d += __shfl_xor(d,  2, 64);
        d += __shfl_xor(d,  1, 64);
        if (lane == 0) wred[wave] = d;
    }
    __syncthreads();
    if (tid == 0)
        Bsum[bx] = (wred[0] + wred[1]) + (wred[2] + wred[3]);
}

__global__ __launch_bounds__(256) void cd_final(
        const float* __restrict__ Bsum, float* __restrict__ out) {
    const int tid = threadIdx.x;
    float s = Bsum[tid];
    __shared__ float red[256];
    red[tid] = s;
    __syncthreads();
    for (int off = 128; off > 0; off >>= 1) {
        if (tid < off) red[tid] += red[tid + off];
        __syncthreads();
    }
    if (tid == 0) out[0] = red[0] * (1.0f / (float)(BATCH * NPTS));
}

extern "C" void kernel_launch(void* const* d_in, const int* in_sizes, int n_in,
                              void* d_out, int out_size, void* d_ws, size_t ws_size,
                              hipStream_t stream) {
    const float* pred = (const float*)d_in[0];
    const float* targ = (const float*)d_in[1];
    float* Bsum = (float*)d_ws;     // 1 KB
    float* out  = (float*)d_out;

    cd_mfma<<<K1_BLOCKS, THREADS, 0, stream>>>(pred, targ, Bsum);
    cd_final<<<1, 256, 0, stream>>>(Bsum, out);
}

// Round 19
// 15.502 us; speedup vs baseline: 2.0601x; 1.0433x over previous
//
#include <hip/hip_runtime.h>

// Chamfer distance, B=8, N=M=4096, fp32 in/out — R12 structure + 4-deep MFMA.
//   d^2 = |q~|^2 + (hi+lo) - 2 q~.b~   via  v_mfma_f32_32x32x8_f16
//   A (32x8): lanes 0-31 row=lane k0-3 {x,y,z,hi}; lanes 32-63 k4-7 {lo,0,0,0}
//   B (8x32): col=lane&31 {-2x,-2y,-2z,1 | 1,0,0,0}
//   C: col = lane&31 (query); in-lane min over rows + shfl32 merge.
// K1 cd_mfma: 256 blocks x 512 thr; 32KB LDS, db staged in TWO 2048-pt
//             generations; per wave 64 tiles/gen with 4-DEEP acc rotation
//             (grid gives 2 waves/SIMD — ILP must hide MFMA+LDS latency).
// K2 cd_final: 1 block (256 thr) sums Bsum deterministically -> loss.

typedef _Float16 f16x4 __attribute__((ext_vector_type(4)));
typedef _Float16 f16x8 __attribute__((ext_vector_type(8)));
typedef float    f32x16 __attribute__((ext_vector_type(16)));

#define BATCH 8
#define NPTS 4096
#define THREADS 512
#define WAVES 8
#define HALF_PTS 2048
#define HALF_TILES (HALF_PTS/32)     // 64
#define K1_BLOCKS 256

__device__ __forceinline__ float min3f(float a, float b, float c) {
    return fminf(fminf(a, b), c);    // -> v_min3_f32
}

__global__ __launch_bounds__(THREADS, 2) void cd_mfma(
        const float* __restrict__ pred,
        const float* __restrict__ targ,
        float* __restrict__ Bsum) {
    __shared__ uint4 sdb[HALF_PTS];      // 32 KB packed db (one generation)
    __shared__ float wred[WAVES];
    const int bx   = blockIdx.x;         // 0..255
    const int tid  = threadIdx.x;
    const int dirb = bx >> 4;            // 0..15
    const int ctg  = bx & 15;            // 0..15
    const int wave = tid >> 6;           // 0..7
    const int lane = tid & 63;
    const int dir  = dirb >> 3;
    const int b    = dirb & 7;
    const float* Qraw = (dir ? targ : pred) + (size_t)b * NPTS * 3;
    const float* Draw = (dir ? pred : targ) + (size_t)b * NPTS * 3;

    // query packet
    const int q = (ctg * WAVES + wave) * 32 + (lane & 31);
    const float* qp = Qraw + (size_t)q * 3;
    _Float16 qhx = (_Float16)qp[0], qhy = (_Float16)qp[1], qhz = (_Float16)qp[2];
    float xr = (float)qhx, yr = (float)qhy, zr = (float)qhz;
    float nq = fmaf(xr, xr, fmaf(yr, yr, zr * zr));
    _Float16 mx = (_Float16)(-2.f * xr), my = (_Float16)(-2.f * yr),
             mz = (_Float16)(-2.f * zr), one = (_Float16)1.f, zz = (_Float16)0.f;
    f16x4 Bf = (lane < 32) ? (f16x4){mx, my, mz, one}
                           : (f16x4){one, zz, zz, zz};

    const f32x16 Z = {};
    const float inf = __uint_as_float(0x7F800000u);
    float m = inf;
    auto fold = [&](const f32x16& a) {
        float s0 = min3f(a[0],  a[1],  a[2]);
        float s1 = min3f(a[3],  a[4],  a[5]);
        float s2 = min3f(a[6],  a[7],  a[8]);
        float s3 = min3f(a[9],  a[10], a[11]);
        float s4 = min3f(a[12], a[13], a[14]);
        float t0 = min3f(s0, s1, s2);
        float t1 = min3f(s3, s4, a[15]);
        m = min3f(m, t0, t1);
    };

    const char* sb = (const char*)sdb;
    const int off0 = (lane & 31) * 16 + ((lane >> 5) << 3);

    #pragma unroll 1
    for (int h = 0; h < 2; ++h) {
        if (h) __syncthreads();          // compute(h-1) done before overwrite

        // stage + f16-pack this half: packet = {x,y,z,hi | lo,0,0,0}
        for (int i = tid; i < HALF_PTS; i += THREADS) {
            const float* p = Draw + (size_t)(h * HALF_PTS + i) * 3;
            _Float16 hx = (_Float16)p[0], hy = (_Float16)p[1], hz = (_Float16)p[2];
            float xf = (float)hx, yf = (float)hy, zf = (float)hz;
            float w  = fmaf(xf, xf, fmaf(yf, yf, zf * zf));
            _Float16 hhi = (_Float16)w;
            _Float16 hlo = (_Float16)(w - (float)hhi);
            f16x8 pkt = {hx, hy, hz, hhi, hlo,
                         (_Float16)0.f, (_Float16)0.f, (_Float16)0.f};
            sdb[i] = __builtin_bit_cast(uint4, pkt);
        }
        __syncthreads();

        // 64 tiles, 4-deep MFMA pipeline (ILP hides MFMA+LDS latency at
        // 2 waves/SIMD actual occupancy)
        int off = off0;
        auto rd = [&]() { f16x4 v = *(const f16x4*)(sb + off); off += 512; return v; };
        f32x16 acc0 = __builtin_amdgcn_mfma_f32_32x32x8f16(rd(), Bf, Z, 0, 0, 0);
        f32x16 acc1 = __builtin_amdgcn_mfma_f32_32x32x8f16(rd(), Bf, Z, 0, 0, 0);
        f32x16 acc2 = __builtin_amdgcn_mfma_f32_32x32x8f16(rd(), Bf, Z, 0, 0, 0);
        f32x16 acc3 = __builtin_amdgcn_mfma_f32_32x32x8f16(rd(), Bf, Z, 0, 0, 0);
        #pragma unroll 4
        for (int j = 4; j < HALF_TILES; j += 4) {
            fold(acc0);
            acc0 = __builtin_amdgcn_mfma_f32_32x32x8f16(rd(), Bf, Z, 0, 0, 0);
            fold(acc1);
            acc1 = __builtin_amdgcn_mfma_f32_32x32x8f16(rd(), Bf, Z, 0, 0, 0);
            fold(acc2);
            acc2 = __builtin_amdgcn_mfma_f32_32x32x8f16(rd(), Bf, Z, 0, 0, 0);
            fold(acc3);
            acc3 = __builtin_amdgcn_mfma_f32_32x32x8f16(rd(), Bf, Z, 0, 0, 0);
        }
        fold(acc0); fold(acc1); fold(acc2); fold(acc3);
        __syncthreads();                 // all reads done before next stage
    }

    // epilogue: merge lane-halves, add |q~|^2, sqrt, sum 32 queries
    m = fminf(m, __shfl_xor(m, 32, 64));
    float d = sqrtf(fmaxf(m + nq, 0.f));
    d += __shfl_xor(d, 16, 64);
    d += __shfl_xor(d,  8, 64);
    d += __shfl_xor(d,  4, 64);
    d += __shfl_xor(d,  2, 64);
    d += __shfl_xor(d,  1, 64);
    if (lane == 0) wred[wave] = d;
    __syncthreads();
    if (tid == 0) {
        float s = ((wred[0] + wred[1]) + (wred[2] + wred[3]))
                + ((wred[4] + wred[5]) + (wred[6] + wred[7]));
        Bsum[bx] = s;
    }
}

__global__ __launch_bounds__(256) void cd_final(
        const float* __restrict__ Bsum, float* __restrict__ out) {
    const int tid = threadIdx.x;
    float s = Bsum[tid];
    __shared__ float red[256];
    red[tid] = s;
    __syncthreads();
    for (int off = 128; off > 0; off >>= 1) {
        if (tid < off) red[tid] += red[tid + off];
        __syncthreads();
    }
    if (tid == 0) out[0] = red[0] * (1.0f / (float)(BATCH * NPTS));
}

extern "C" void kernel_launch(void* const* d_in, const int* in_sizes, int n_in,
                              void* d_out, int out_size, void* d_ws, size_t ws_size,
                              hipStream_t stream) {
    const float* pred = (const float*)d_in[0];
    const float* targ = (const float*)d_in[1];
    float* Bsum = (float*)d_ws;     // 1 KB
    float* out  = (float*)d_out;

    cd_mfma<<<K1_BLOCKS, THREADS, 0, stream>>>(pred, targ, Bsum);
    cd_final<<<1, 256, 0, stream>>>(Bsum, out);
}